// Round 2
// baseline (17636.148 us; speedup 1.0000x reference)
//
#include <hip/hip_runtime.h>
#include <hip/hip_bf16.h>
#include <hip/hip_cooperative_groups.h>
#include <stdint.h>

namespace cg = cooperative_groups;

#define B_  64
#define T_  256
#define E_  1024
#define UN  1024
#define KIN 2048     // E_+UN
#define N3  3072     // 3*UN
#define M_  16384    // B_*T_

typedef __attribute__((ext_vector_type(8))) short short8;
typedef __attribute__((ext_vector_type(4))) float f32x4;

static __device__ __forceinline__ float bf2f(short s) {
    union { float f; uint32_t u; } c; c.u = ((uint32_t)(uint16_t)s) << 16; return c.f;
}
static __device__ __forceinline__ short f2bf(float f) {
    union { float f; uint32_t u; } c; c.f = f;
    uint32_t u = c.u;
    uint32_t r = (u + 0x7fffu + ((u >> 16) & 1u)) >> 16;   // round-nearest-even
    return (short)(uint16_t)r;
}

// ---------------- prep: weights -> bf16 transposed layouts ----------------
__global__ __launch_bounds__(256)
void k_prep_w(const float* __restrict__ Wr, const float* __restrict__ Ur, const float* __restrict__ Cr,
              const float* __restrict__ Wz, const float* __restrict__ Uz, const float* __restrict__ Cz,
              const float* __restrict__ Wc, const float* __restrict__ Uc, const float* __restrict__ Cc,
              short* __restrict__ WcatT, short* __restrict__ UcatT, short* __restrict__ UcT)
{
    __shared__ float tile[32][33];
    int m = blockIdx.z;
    const float* src; short* dst; int ld, noff, koff;
    switch (m) {
      case 0: src=Cr; dst=WcatT; ld=KIN;  noff=0;    koff=0;    break;
      case 1: src=Wr; dst=WcatT; ld=KIN;  noff=0;    koff=1024; break;
      case 2: src=Cz; dst=WcatT; ld=KIN;  noff=1024; koff=0;    break;
      case 3: src=Wz; dst=WcatT; ld=KIN;  noff=1024; koff=1024; break;
      case 4: src=Cc; dst=WcatT; ld=KIN;  noff=2048; koff=0;    break;
      case 5: src=Wc; dst=WcatT; ld=KIN;  noff=2048; koff=1024; break;
      case 6: src=Ur; dst=UcatT; ld=1024; noff=0;    koff=0;    break;
      case 7: src=Uz; dst=UcatT; ld=1024; noff=1024; koff=0;    break;
      default: src=Uc; dst=UcT;  ld=1024; noff=0;    koff=0;    break;
    }
    int n0 = blockIdx.x * 32, k0 = blockIdx.y * 32;
    int tx = threadIdx.x, ty = threadIdx.y;      // block (32,8)
    #pragma unroll
    for (int i = 0; i < 32; i += 8)
        tile[ty + i][tx] = src[(long)(k0 + ty + i) * 1024 + (n0 + tx)];
    __syncthreads();
    #pragma unroll
    for (int i = 0; i < 32; i += 8)
        dst[(long)(noff + n0 + ty + i) * ld + koff + k0 + tx] = f2bf(tile[tx][ty + i]);
}

// ---------------- prep: X -> bf16 ----------------
__global__ __launch_bounds__(256)
void k_prep_x(const float* __restrict__ X, short* __restrict__ Xb, long n8)
{
    long i = (long)blockIdx.x * blockDim.x + threadIdx.x;
    long stride = (long)gridDim.x * blockDim.x;
    for (; i < n8; i += stride) {
        const float4* p = (const float4*)(X + i * 8);
        float4 a = p[0], b = p[1];
        short8 o;
        o[0]=f2bf(a.x); o[1]=f2bf(a.y); o[2]=f2bf(a.z); o[3]=f2bf(a.w);
        o[4]=f2bf(b.x); o[5]=f2bf(b.y); o[6]=f2bf(b.z); o[7]=f2bf(b.w);
        *(short8*)(Xb + i * 8) = o;
    }
}

__global__ __launch_bounds__(256)
void k_init_h(const float* __restrict__ h0, float* __restrict__ h, short* __restrict__ hb)
{
    int i = blockIdx.x * 256 + threadIdx.x;   // 256 blocks -> 65536
    float v = h0[i];
    h[i] = v; hb[i] = f2bf(v);
}

// ---------------- phase 1: P = Xb @ Wcat, stored t-major: P[(t*64+b)][n] ----------------
__global__ __launch_bounds__(256)
void k_gemm_x(const short* __restrict__ Xb, const short* __restrict__ WcatT, short* __restrict__ P)
{
    __shared__ short As[128 * 64];
    __shared__ short Bs[128 * 64];
    int tid = threadIdx.x;
    int lane = tid & 63, wave = tid >> 6;
    int i0 = blockIdx.y * 128;    // M block
    int n0 = blockIdx.x * 128;    // N block
    int wrow = (wave >> 1) * 64, wcol = (wave & 1) * 64;
    f32x4 acc[4][4] = {};

    for (int k0 = 0; k0 < KIN; k0 += 64) {
        __syncthreads();
        #pragma unroll
        for (int j = 0; j < 4; j++) {
            int e = (j * 256 + tid) * 8;
            int row = e >> 6, k = e & 63;
            short8 va = *(const short8*)(Xb    + (long)(i0 + row) * KIN + k0 + k);
            short8 vb = *(const short8*)(WcatT + (long)(n0 + row) * KIN + k0 + k);
            int byt = row * 128 + ((k * 2) ^ ((row & 7) << 4));   // XOR swizzle
            *(short8*)((char*)As + byt) = va;
            *(short8*)((char*)Bs + byt) = vb;
        }
        __syncthreads();
        #pragma unroll
        for (int kk = 0; kk < 64; kk += 32) {
            short8 af[4], bfr[4];
            int kel = kk + (lane >> 4) * 8;
            #pragma unroll
            for (int rt = 0; rt < 4; rt++) {
                int row = wrow + rt * 16 + (lane & 15);
                int byt = row * 128 + ((kel * 2) ^ ((row & 7) << 4));
                af[rt] = *(const short8*)((const char*)As + byt);
            }
            #pragma unroll
            for (int ct = 0; ct < 4; ct++) {
                int row = wcol + ct * 16 + (lane & 15);
                int byt = row * 128 + ((kel * 2) ^ ((row & 7) << 4));
                bfr[ct] = *(const short8*)((const char*)Bs + byt);
            }
            #pragma unroll
            for (int rt = 0; rt < 4; rt++)
                #pragma unroll
                for (int ct = 0; ct < 4; ct++)
                    acc[rt][ct] = __builtin_amdgcn_mfma_f32_16x16x32_bf16(af[rt], bfr[ct], acc[rt][ct], 0, 0, 0);
        }
    }
    #pragma unroll
    for (int rt = 0; rt < 4; rt++)
      #pragma unroll
      for (int ct = 0; ct < 4; ct++)
        #pragma unroll
        for (int r = 0; r < 4; r++) {
            int row = i0 + wrow + rt * 16 + (lane >> 4) * 4 + r;   // = b*256 + t
            int prow = ((row & 255) << 6) | (row >> 8);            // t*64 + b
            int col = n0 + wcol + ct * 16 + (lane & 15);
            P[(long)prow * N3 + col] = f2bf(acc[rt][ct][r]);
        }
}

// ---------------- persistent recurrence kernel (cooperative) ----------------
// 32 blocks x 256 thr = 128 waves.
// Phase A: wave wid -> 64x16 strip (cols wid*16) of rz = hardsig(P_rz[t] + h@U_rz)
// Phase B: waves 0..63 -> 64x16 strip of hc = tanh(P_c[t] + (h.r)@U); h update.
__global__ __launch_bounds__(256)
void k_recur(const short* __restrict__ UcatT, const short* __restrict__ UcT,
             const short* __restrict__ P,
             float* __restrict__ h, short* __restrict__ hb,
             short* __restrict__ rh, float* __restrict__ zbuf,
             float* __restrict__ out)
{
    cg::grid_group grid = cg::this_grid();
    int lane = threadIdx.x & 63, wave = threadIdx.x >> 6;
    int wid = blockIdx.x * 4 + wave;          // 0..127
    int lrow = lane & 15, lk = (lane >> 4) * 8;
    int col16 = lane & 15, rquad = (lane >> 4) * 4;

    for (int t = 0; t < T_; t++) {
        // -------- phase A --------
        {
            int n0 = wid * 16;                // 0..2047
            int col = n0 + col16;
            // preload P slice (independent of MFMA chain -> issues early)
            float pv[4][4];
            const short* Pb = P + (long)t * 64 * N3 + col;
            #pragma unroll
            for (int rt = 0; rt < 4; rt++)
                #pragma unroll
                for (int r = 0; r < 4; r++)
                    pv[rt][r] = bf2f(Pb[(long)(rt * 16 + rquad + r) * N3]);

            f32x4 acc[4] = {};
            const short8* Bp = (const short8*)(UcatT + (n0 + lrow) * 1024 + lk);
            #pragma unroll 8
            for (int kk = 0; kk < 32; kk++) {
                short8 bf = Bp[kk * 4];
                #pragma unroll
                for (int rt = 0; rt < 4; rt++) {
                    short8 af = *(const short8*)(hb + (rt * 16 + lrow) * 1024 + kk * 32 + lk);
                    acc[rt] = __builtin_amdgcn_mfma_f32_16x16x32_bf16(af, bf, acc[rt], 0, 0, 0);
                }
            }
            #pragma unroll
            for (int rt = 0; rt < 4; rt++)
                #pragma unroll
                for (int r = 0; r < 4; r++) {
                    int b = rt * 16 + rquad + r;
                    float pre = acc[rt][r] + pv[rt][r];
                    float v = fminf(fmaxf(0.2f * pre + 0.5f, 0.f), 1.f);
                    if (col < 1024)
                        rh[b * 1024 + col] = f2bf(v * h[b * 1024 + col]);
                    else
                        zbuf[b * 1024 + (col - 1024)] = v;
                }
        }
        grid.sync();
        // -------- phase B --------
        if (wid < 64) {
            int n0 = wid * 16;
            int col = n0 + col16;
            float pv[4][4];
            const short* Pb = P + (long)t * 64 * N3 + 2048 + col;
            #pragma unroll
            for (int rt = 0; rt < 4; rt++)
                #pragma unroll
                for (int r = 0; r < 4; r++)
                    pv[rt][r] = bf2f(Pb[(long)(rt * 16 + rquad + r) * N3]);

            f32x4 acc[4] = {};
            const short8* Bp = (const short8*)(UcT + (n0 + lrow) * 1024 + lk);
            #pragma unroll 8
            for (int kk = 0; kk < 32; kk++) {
                short8 bf = Bp[kk * 4];
                #pragma unroll
                for (int rt = 0; rt < 4; rt++) {
                    short8 af = *(const short8*)(rh + (rt * 16 + lrow) * 1024 + kk * 32 + lk);
                    acc[rt] = __builtin_amdgcn_mfma_f32_16x16x32_bf16(af, bf, acc[rt], 0, 0, 0);
                }
            }
            #pragma unroll
            for (int rt = 0; rt < 4; rt++)
                #pragma unroll
                for (int r = 0; r < 4; r++) {
                    int b = rt * 16 + rquad + r;
                    float pre = acc[rt][r] + pv[rt][r];
                    float hc = tanhf(pre);
                    float z  = zbuf[b * 1024 + col];
                    float ho = h[b * 1024 + col];
                    float hn = (1.f - z) * ho + z * hc;
                    h[b * 1024 + col]  = hn;
                    hb[b * 1024 + col] = f2bf(hn);
                    out[((long)b * T_ + t) * 1024 + col] = hn;
                }
        }
        grid.sync();
    }
}

// ---------------- fallback per-step kernels (t-major P) ----------------
__global__ __launch_bounds__(256)
void k_stepA(const short* __restrict__ hb, const short* __restrict__ UcatT,
             const short* __restrict__ P, const float* __restrict__ h,
             short* __restrict__ rh, float* __restrict__ zbuf, int t)
{
    int lane = threadIdx.x & 63, wave = threadIdx.x >> 6;
    int wid = blockIdx.x * 4 + wave;      // 0..511
    int ct = wid & 127, rt = wid >> 7;
    int r0 = rt * 16, n0 = ct * 16;
    int lrow = lane & 15, lk = (lane >> 4) * 8;
    f32x4 acc = {0.f, 0.f, 0.f, 0.f};
    const short8* Aptr = (const short8*)(hb    + (r0 + lrow) * 1024 + lk);
    const short8* Bptr = (const short8*)(UcatT + (n0 + lrow) * 1024 + lk);
    #pragma unroll 8
    for (int kk = 0; kk < 32; kk++)
        acc = __builtin_amdgcn_mfma_f32_16x16x32_bf16(Aptr[kk * 4], Bptr[kk * 4], acc, 0, 0, 0);

    int col = n0 + (lane & 15);
    int brb = r0 + (lane >> 4) * 4;
    #pragma unroll
    for (int r = 0; r < 4; r++) {
        int b = brb + r;
        float pre = acc[r] + bf2f(P[((long)t * 64 + b) * N3 + col]);
        float v = fminf(fmaxf(0.2f * pre + 0.5f, 0.f), 1.f);
        if (col < 1024)
            rh[b * 1024 + col] = f2bf(v * h[b * 1024 + col]);
        else
            zbuf[b * 1024 + (col - 1024)] = v;
    }
}

__global__ __launch_bounds__(256)
void k_stepB(const short* __restrict__ rh, const short* __restrict__ UcT,
             const short* __restrict__ P, const float* __restrict__ zbuf,
             float* __restrict__ h, short* __restrict__ hb,
             float* __restrict__ out, int t)
{
    int lane = threadIdx.x & 63, wave = threadIdx.x >> 6;
    int wid = blockIdx.x * 4 + wave;      // 0..255
    int ct = wid & 63, rt = wid >> 6;
    int r0 = rt * 16, n0 = ct * 16;
    int lrow = lane & 15, lk = (lane >> 4) * 8;
    f32x4 acc = {0.f, 0.f, 0.f, 0.f};
    const short8* Aptr = (const short8*)(rh  + (r0 + lrow) * 1024 + lk);
    const short8* Bptr = (const short8*)(UcT + (n0 + lrow) * 1024 + lk);
    #pragma unroll 8
    for (int kk = 0; kk < 32; kk++)
        acc = __builtin_amdgcn_mfma_f32_16x16x32_bf16(Aptr[kk * 4], Bptr[kk * 4], acc, 0, 0, 0);

    int col = n0 + (lane & 15);
    int brb = r0 + (lane >> 4) * 4;
    #pragma unroll
    for (int r = 0; r < 4; r++) {
        int b = brb + r;
        float pre = acc[r] + bf2f(P[((long)t * 64 + b) * N3 + 2048 + col]);
        float hc = tanhf(pre);
        float z  = zbuf[b * 1024 + col];
        float ho = h[b * 1024 + col];
        float hn = (1.f - z) * ho + z * hc;
        h[b * 1024 + col]  = hn;
        hb[b * 1024 + col] = f2bf(hn);
        out[((long)b * T_ + t) * 1024 + col] = hn;
    }
}

extern "C" void kernel_launch(void* const* d_in, const int* in_sizes, int n_in,
                              void* d_out, int out_size, void* d_ws, size_t ws_size,
                              hipStream_t stream)
{
    (void)in_sizes; (void)n_in; (void)out_size; (void)ws_size;
    const float* X   = (const float*)d_in[0];
    const float* h0  = (const float*)d_in[1];
    const float* W_r = (const float*)d_in[2];
    const float* U_r = (const float*)d_in[3];
    const float* C_r = (const float*)d_in[4];
    const float* W_z = (const float*)d_in[5];
    const float* U_z = (const float*)d_in[6];
    const float* C_z = (const float*)d_in[7];
    const float* W   = (const float*)d_in[8];
    const float* U   = (const float*)d_in[9];
    const float* C   = (const float*)d_in[10];

    char* ws = (char*)d_ws;
    size_t off = 0;
    short* WcatT = (short*)(ws + off); off += (size_t)N3 * KIN * 2;
    short* UcatT = (short*)(ws + off); off += (size_t)2048 * 1024 * 2;
    short* UcT   = (short*)(ws + off); off += (size_t)1024 * 1024 * 2;
    short* Xb    = (short*)(ws + off); off += (size_t)M_ * KIN * 2;
    short* P     = (short*)(ws + off); off += (size_t)M_ * N3 * 2;
    float* h     = (float*)(ws + off); off += (size_t)B_ * UN * 4;
    short* hb    = (short*)(ws + off); off += (size_t)B_ * UN * 2;
    short* rh    = (short*)(ws + off); off += (size_t)B_ * UN * 2;
    float* zbuf  = (float*)(ws + off); off += (size_t)B_ * UN * 4;

    k_prep_w<<<dim3(32, 32, 9), dim3(32, 8), 0, stream>>>(W_r, U_r, C_r, W_z, U_z, C_z, W, U, C,
                                                          WcatT, UcatT, UcT);
    k_prep_x<<<2048, 256, 0, stream>>>(X, Xb, (long)M_ * KIN / 8);
    k_init_h<<<256, 256, 0, stream>>>(h0, h, hb);
    k_gemm_x<<<dim3(N3 / 128, M_ / 128), 256, 0, stream>>>(Xb, WcatT, P);

    float* out = (float*)d_out;
    void* args[] = { (void*)&UcatT, (void*)&UcT, (void*)&P, (void*)&h, (void*)&hb,
                     (void*)&rh, (void*)&zbuf, (void*)&out };
    hipError_t e = hipLaunchCooperativeKernel((const void*)k_recur, dim3(32), dim3(256),
                                              args, 0, stream);
    if (e != hipSuccess) {
        // fallback: per-step launches
        for (int t = 0; t < T_; t++) {
            k_stepA<<<128, 256, 0, stream>>>(hb, UcatT, P, h, rh, zbuf, t);
            k_stepB<<<64, 256, 0, stream>>>(rh, UcT, P, zbuf, h, hb, out, t);
        }
    }
}

// Round 3
// 10021.455 us; speedup vs baseline: 1.7598x; 1.7598x over previous
//
#include <hip/hip_runtime.h>
#include <hip/hip_bf16.h>
#include <stdint.h>

#define B_   64
#define T_   256
#define KIN  2048
#define N3   3072
#define M_   16384
#define NBLK 16
#define NTHR 512

typedef __attribute__((ext_vector_type(8))) short short8;
typedef __attribute__((ext_vector_type(4))) float f32x4;
typedef unsigned long long u64;

static __device__ __forceinline__ float bf2f(short s) {
    union { float f; uint32_t u; } c; c.u = ((uint32_t)(uint16_t)s) << 16; return c.f;
}
static __device__ __forceinline__ short f2bf(float f) {
    union { float f; uint32_t u; } c; c.f = f;
    uint32_t u = c.u;
    uint32_t r = (u + 0x7fffu + ((u >> 16) & 1u)) >> 16;   // round-nearest-even
    return (short)(uint16_t)r;
}

// ---------------- prep: weights -> bf16 transposed layouts ----------------
__global__ __launch_bounds__(256)
void k_prep_w(const float* __restrict__ Wr, const float* __restrict__ Ur, const float* __restrict__ Cr,
              const float* __restrict__ Wz, const float* __restrict__ Uz, const float* __restrict__ Cz,
              const float* __restrict__ Wc, const float* __restrict__ Uc, const float* __restrict__ Cc,
              short* __restrict__ WcatT, short* __restrict__ UcatT, short* __restrict__ UcT)
{
    __shared__ float tile[32][33];
    int m = blockIdx.z;
    const float* src; short* dst; int ld, noff, koff;
    switch (m) {
      case 0: src=Cr; dst=WcatT; ld=KIN;  noff=0;    koff=0;    break;
      case 1: src=Wr; dst=WcatT; ld=KIN;  noff=0;    koff=1024; break;
      case 2: src=Cz; dst=WcatT; ld=KIN;  noff=1024; koff=0;    break;
      case 3: src=Wz; dst=WcatT; ld=KIN;  noff=1024; koff=1024; break;
      case 4: src=Cc; dst=WcatT; ld=KIN;  noff=2048; koff=0;    break;
      case 5: src=Wc; dst=WcatT; ld=KIN;  noff=2048; koff=1024; break;
      case 6: src=Ur; dst=UcatT; ld=1024; noff=0;    koff=0;    break;
      case 7: src=Uz; dst=UcatT; ld=1024; noff=1024; koff=0;    break;
      default: src=Uc; dst=UcT;  ld=1024; noff=0;    koff=0;    break;
    }
    int n0 = blockIdx.x * 32, k0 = blockIdx.y * 32;
    int tx = threadIdx.x, ty = threadIdx.y;      // block (32,8)
    #pragma unroll
    for (int i = 0; i < 32; i += 8)
        tile[ty + i][tx] = src[(long)(k0 + ty + i) * 1024 + (n0 + tx)];
    __syncthreads();
    #pragma unroll
    for (int i = 0; i < 32; i += 8)
        dst[(long)(noff + n0 + ty + i) * ld + koff + k0 + tx] = f2bf(tile[tx][ty + i]);
}

// ---------------- prep: X -> bf16 ----------------
__global__ __launch_bounds__(256)
void k_prep_x(const float* __restrict__ X, short* __restrict__ Xb, long n8)
{
    long i = (long)blockIdx.x * blockDim.x + threadIdx.x;
    long stride = (long)gridDim.x * blockDim.x;
    for (; i < n8; i += stride) {
        const float4* p = (const float4*)(X + i * 8);
        float4 a = p[0], b = p[1];
        short8 o;
        o[0]=f2bf(a.x); o[1]=f2bf(a.y); o[2]=f2bf(a.z); o[3]=f2bf(a.w);
        o[4]=f2bf(b.x); o[5]=f2bf(b.y); o[6]=f2bf(b.z); o[7]=f2bf(b.w);
        *(short8*)(Xb + i * 8) = o;
    }
}

__global__ __launch_bounds__(256)
void k_init_h(const float* __restrict__ h0, float* __restrict__ h, short* __restrict__ hb,
              uint32_t* __restrict__ barcnt)
{
    int i = blockIdx.x * 256 + threadIdx.x;   // 256 blocks -> 65536
    float v = h0[i];
    h[i] = v; hb[i] = f2bf(v);
    if (i == 0) *barcnt = 0;
}

// ---------------- phase 1: P = Xb @ Wcat, stored t-major: P[(t*64+b)][n] ----------------
__global__ __launch_bounds__(256)
void k_gemm_x(const short* __restrict__ Xb, const short* __restrict__ WcatT, short* __restrict__ P)
{
    __shared__ short As[128 * 64];
    __shared__ short Bs[128 * 64];
    int tid = threadIdx.x;
    int lane = tid & 63, wave = tid >> 6;
    int i0 = blockIdx.y * 128;    // M block
    int n0 = blockIdx.x * 128;    // N block
    int wrow = (wave >> 1) * 64, wcol = (wave & 1) * 64;
    f32x4 acc[4][4] = {};

    for (int k0 = 0; k0 < KIN; k0 += 64) {
        __syncthreads();
        #pragma unroll
        for (int j = 0; j < 4; j++) {
            int e = (j * 256 + tid) * 8;
            int row = e >> 6, k = e & 63;
            short8 va = *(const short8*)(Xb    + (long)(i0 + row) * KIN + k0 + k);
            short8 vb = *(const short8*)(WcatT + (long)(n0 + row) * KIN + k0 + k);
            int byt = row * 128 + ((k * 2) ^ ((row & 7) << 4));   // XOR swizzle
            *(short8*)((char*)As + byt) = va;
            *(short8*)((char*)Bs + byt) = vb;
        }
        __syncthreads();
        #pragma unroll
        for (int kk = 0; kk < 64; kk += 32) {
            short8 af[4], bfr[4];
            int kel = kk + (lane >> 4) * 8;
            #pragma unroll
            for (int rt = 0; rt < 4; rt++) {
                int row = wrow + rt * 16 + (lane & 15);
                int byt = row * 128 + ((kel * 2) ^ ((row & 7) << 4));
                af[rt] = *(const short8*)((const char*)As + byt);
            }
            #pragma unroll
            for (int ct = 0; ct < 4; ct++) {
                int row = wcol + ct * 16 + (lane & 15);
                int byt = row * 128 + ((kel * 2) ^ ((row & 7) << 4));
                bfr[ct] = *(const short8*)((const char*)Bs + byt);
            }
            #pragma unroll
            for (int rt = 0; rt < 4; rt++)
                #pragma unroll
                for (int ct = 0; ct < 4; ct++)
                    acc[rt][ct] = __builtin_amdgcn_mfma_f32_16x16x32_bf16(af[rt], bfr[ct], acc[rt][ct], 0, 0, 0);
        }
    }
    #pragma unroll
    for (int rt = 0; rt < 4; rt++)
      #pragma unroll
      for (int ct = 0; ct < 4; ct++)
        #pragma unroll
        for (int r = 0; r < 4; r++) {
            int row = i0 + wrow + rt * 16 + (lane >> 4) * 4 + r;   // = b*256 + t
            int prow = ((row & 255) << 6) | (row >> 8);            // t*64 + b
            int col = n0 + wcol + ct * 16 + (lane & 15);
            P[(long)prow * N3 + col] = f2bf(acc[rt][ct][r]);
        }
}

// ---------------- hand-rolled grid barrier (relaxed agent atomics) ----------------
static __device__ __forceinline__ void gbar(uint32_t* barcnt, uint32_t* bseq)
{
    __syncthreads();                 // drains vmcnt per wave -> all atomic stores complete
    *bseq += 1;
    if (threadIdx.x == 0) {
        __hip_atomic_fetch_add(barcnt, 1u, __ATOMIC_RELAXED, __HIP_MEMORY_SCOPE_AGENT);
        uint32_t tgt = *bseq * (uint32_t)NBLK;
        while (__hip_atomic_load(barcnt, __ATOMIC_RELAXED, __HIP_MEMORY_SCOPE_AGENT) < tgt) { }
    }
    __syncthreads();
}

// ---------------- persistent recurrence kernel ----------------
// 16 blocks x 512 thr (8 waves). Block owns hidden cols [blk*64, blk*64+64).
// Phase A: waves 0-3 -> r cols, waves 4-7 -> z cols (each a 64x16 strip, K=1024 over staged hb).
// Phase B: wave w -> col-tile (w&3), row-half (w>>2) of 64x64 candidate tile over staged rh.
// Cross-block data (rh, hb) published/read ONLY via agent-scope atomic u64 ops.
__global__ __launch_bounds__(NTHR)
void k_recur2(const short* __restrict__ UcatT, const short* __restrict__ UcT,
              const short* __restrict__ P, const float* __restrict__ hG,
              u64* __restrict__ hbG, u64* __restrict__ rhG,
              uint32_t* __restrict__ barcnt, float* __restrict__ out)
{
    __shared__ short stage[64 * 512];    // 64 KB: K-chunk of A-operand, XOR-swizzled
    __shared__ float h_lds[64 * 68];     // owner-local h (f32), padded stride
    __shared__ float z_lds[64 * 68];     // owner-local z
    __shared__ short tscr[8 * 256];      // per-wave 16x16 transpose scratch

    const int tid  = threadIdx.x;
    const int lane = tid & 63, w = tid >> 6;
    const int col16 = lane & 15, rquad = (lane >> 4) * 4;
    const int lrow = lane & 15, lk = (lane >> 4) * 8;
    const int Cb = blockIdx.x * 64;

    for (int i = tid; i < 64 * 64; i += NTHR) {
        int b = i >> 6, cl = i & 63;
        h_lds[b * 68 + cl] = hG[b * 1024 + Cb + cl];
    }

    const int nrowA = (w < 4) ? (Cb + w * 16) : (1024 + Cb + (w - 4) * 16);
    const short* BbaseA = UcatT + (nrowA + lrow) * 1024 + lk;
    const short* BbaseB = UcT + (Cb + (w & 3) * 16 + lrow) * 1024 + lk;
    const int rowB0 = (w >> 2) * 32;
    const int clB0 = (w & 3) * 16;

    uint32_t bseq = 0;

    for (int t = 0; t < T_; t++) {
        // ======== phase A: rz = hardsig(P_rz + h @ U_rz) ========
        float pv[4][4];
        {
            const short* Pb = P + (long)t * 64 * N3 + nrowA + col16;
            #pragma unroll
            for (int rt = 0; rt < 4; rt++)
                #pragma unroll
                for (int r = 0; r < 4; r++)
                    pv[rt][r] = bf2f(Pb[(rt * 16 + rquad + r) * N3]);
        }
        f32x4 acc[4] = {};
        #pragma unroll
        for (int c = 0; c < 2; c++) {
            {   // stage hb chunk c (two-pass: issue all loads, then LDS writes)
                const u64* src = (const u64*)hbG + c * 128;
                u64 v[16];
                #pragma unroll
                for (int i = 0; i < 16; i++) {
                    int e = tid + i * NTHR;
                    v[i] = __hip_atomic_load((u64*)(src + (e >> 7) * 256 + (e & 127)),
                                             __ATOMIC_RELAXED, __HIP_MEMORY_SCOPE_AGENT);
                }
                #pragma unroll
                for (int i = 0; i < 16; i++) {
                    int e = tid + i * NTHR;
                    int row = e >> 7, q = e & 127;
                    *(u64*)((char*)stage + row * 1024 + ((q * 8) ^ ((row & 7) << 4))) = v[i];
                }
            }
            __syncthreads();
            #pragma unroll
            for (int kk = 0; kk < 16; kk++) {
                short8 bf = *(const short8*)(BbaseA + c * 512 + kk * 32);
                #pragma unroll
                for (int rt = 0; rt < 4; rt++) {
                    int row = rt * 16 + lrow;
                    int kc = kk * 32 + lk;
                    short8 af = *(const short8*)((const char*)stage + row * 1024 + ((kc * 2) ^ ((row & 7) << 4)));
                    acc[rt] = __builtin_amdgcn_mfma_f32_16x16x32_bf16(af, bf, acc[rt], 0, 0, 0);
                }
            }
            __syncthreads();
        }
        if (w < 4) {                       // r-waves: rh = r*h, publish transposed->k-contiguous
            int cl0 = w * 16;
            #pragma unroll
            for (int rt = 0; rt < 4; rt++) {
                #pragma unroll
                for (int r = 0; r < 4; r++) {
                    int b = rt * 16 + rquad + r;
                    float pre = acc[rt][r] + pv[rt][r];
                    float v = fminf(fmaxf(0.2f * pre + 0.5f, 0.f), 1.f);
                    tscr[w * 256 + (rquad + r) * 16 + col16] = f2bf(v * h_lds[b * 68 + cl0 + col16]);
                }
                asm volatile("s_waitcnt lgkmcnt(0)" ::: "memory");
                u64 vv = *(const u64*)((const char*)tscr + w * 512 + (lane & 15) * 32 + (lane >> 4) * 8);
                asm volatile("s_waitcnt lgkmcnt(0)" ::: "memory");
                int b = rt * 16 + (lane & 15);
                __hip_atomic_store(rhG + b * 256 + ((Cb + cl0) >> 2) + (lane >> 4), vv,
                                   __ATOMIC_RELAXED, __HIP_MEMORY_SCOPE_AGENT);
            }
        } else {                           // z-waves: z stays block-local
            int cl0 = (w - 4) * 16;
            #pragma unroll
            for (int rt = 0; rt < 4; rt++)
                #pragma unroll
                for (int r = 0; r < 4; r++) {
                    int b = rt * 16 + rquad + r;
                    float pre = acc[rt][r] + pv[rt][r];
                    z_lds[b * 68 + cl0 + col16] = fminf(fmaxf(0.2f * pre + 0.5f, 0.f), 1.f);
                }
        }
        gbar(barcnt, &bseq);

        // ======== phase B: hc = tanh(P_c + rh @ U); h update ========
        float pv2[2][4];
        {
            const short* Pb = P + (long)t * 64 * N3 + 2048 + Cb + clB0 + col16;
            #pragma unroll
            for (int j = 0; j < 2; j++)
                #pragma unroll
                for (int r = 0; r < 4; r++)
                    pv2[j][r] = bf2f(Pb[(rowB0 + j * 16 + rquad + r) * N3]);
        }
        f32x4 acc2[2] = {};
        #pragma unroll
        for (int c = 0; c < 2; c++) {
            {
                const u64* src = (const u64*)rhG + c * 128;
                u64 v[16];
                #pragma unroll
                for (int i = 0; i < 16; i++) {
                    int e = tid + i * NTHR;
                    v[i] = __hip_atomic_load((u64*)(src + (e >> 7) * 256 + (e & 127)),
                                             __ATOMIC_RELAXED, __HIP_MEMORY_SCOPE_AGENT);
                }
                #pragma unroll
                for (int i = 0; i < 16; i++) {
                    int e = tid + i * NTHR;
                    int row = e >> 7, q = e & 127;
                    *(u64*)((char*)stage + row * 1024 + ((q * 8) ^ ((row & 7) << 4))) = v[i];
                }
            }
            __syncthreads();
            #pragma unroll
            for (int kk = 0; kk < 16; kk++) {
                short8 bf = *(const short8*)(BbaseB + c * 512 + kk * 32);
                #pragma unroll
                for (int j = 0; j < 2; j++) {
                    int row = rowB0 + j * 16 + lrow;
                    int kc = kk * 32 + lk;
                    short8 af = *(const short8*)((const char*)stage + row * 1024 + ((kc * 2) ^ ((row & 7) << 4)));
                    acc2[j] = __builtin_amdgcn_mfma_f32_16x16x32_bf16(af, bf, acc2[j], 0, 0, 0);
                }
            }
            __syncthreads();
        }
        #pragma unroll
        for (int j = 0; j < 2; j++) {
            #pragma unroll
            for (int r = 0; r < 4; r++) {
                int b = rowB0 + j * 16 + rquad + r;
                float pre = acc2[j][r] + pv2[j][r];
                float hc = tanhf(pre);
                float z  = z_lds[b * 68 + clB0 + col16];
                float ho = h_lds[b * 68 + clB0 + col16];
                float hn = (1.f - z) * ho + z * hc;
                h_lds[b * 68 + clB0 + col16] = hn;
                out[((long)b * T_ + t) * 1024 + Cb + clB0 + col16] = hn;
                tscr[w * 256 + (rquad + r) * 16 + col16] = f2bf(hn);
            }
            asm volatile("s_waitcnt lgkmcnt(0)" ::: "memory");
            u64 vv = *(const u64*)((const char*)tscr + w * 512 + (lane & 15) * 32 + (lane >> 4) * 8);
            asm volatile("s_waitcnt lgkmcnt(0)" ::: "memory");
            int b = rowB0 + j * 16 + (lane & 15);
            __hip_atomic_store(hbG + b * 256 + ((Cb + clB0) >> 2) + (lane >> 4), vv,
                               __ATOMIC_RELAXED, __HIP_MEMORY_SCOPE_AGENT);
        }
        gbar(barcnt, &bseq);
    }
}

// ---------------- fallback per-step kernels (t-major P) ----------------
__global__ __launch_bounds__(256)
void k_stepA(const short* __restrict__ hb, const short* __restrict__ UcatT,
             const short* __restrict__ P, const float* __restrict__ h,
             short* __restrict__ rh, float* __restrict__ zbuf, int t)
{
    int lane = threadIdx.x & 63, wave = threadIdx.x >> 6;
    int wid = blockIdx.x * 4 + wave;
    int ct = wid & 127, rt = wid >> 7;
    int r0 = rt * 16, n0 = ct * 16;
    int lrow = lane & 15, lk = (lane >> 4) * 8;
    f32x4 acc = {0.f, 0.f, 0.f, 0.f};
    const short8* Aptr = (const short8*)(hb    + (r0 + lrow) * 1024 + lk);
    const short8* Bptr = (const short8*)(UcatT + (n0 + lrow) * 1024 + lk);
    #pragma unroll 8
    for (int kk = 0; kk < 32; kk++)
        acc = __builtin_amdgcn_mfma_f32_16x16x32_bf16(Aptr[kk * 4], Bptr[kk * 4], acc, 0, 0, 0);

    int col = n0 + (lane & 15);
    int brb = r0 + (lane >> 4) * 4;
    #pragma unroll
    for (int r = 0; r < 4; r++) {
        int b = brb + r;
        float pre = acc[r] + bf2f(P[((long)t * 64 + b) * N3 + col]);
        float v = fminf(fmaxf(0.2f * pre + 0.5f, 0.f), 1.f);
        if (col < 1024)
            rh[b * 1024 + col] = f2bf(v * h[b * 1024 + col]);
        else
            zbuf[b * 1024 + (col - 1024)] = v;
    }
}

__global__ __launch_bounds__(256)
void k_stepB(const short* __restrict__ rh, const short* __restrict__ UcT,
             const short* __restrict__ P, const float* __restrict__ zbuf,
             float* __restrict__ h, short* __restrict__ hb,
             float* __restrict__ out, int t)
{
    int lane = threadIdx.x & 63, wave = threadIdx.x >> 6;
    int wid = blockIdx.x * 4 + wave;
    int ct = wid & 63, rt = wid >> 6;
    int r0 = rt * 16, n0 = ct * 16;
    int lrow = lane & 15, lk = (lane >> 4) * 8;
    f32x4 acc = {0.f, 0.f, 0.f, 0.f};
    const short8* Aptr = (const short8*)(rh  + (r0 + lrow) * 1024 + lk);
    const short8* Bptr = (const short8*)(UcT + (n0 + lrow) * 1024 + lk);
    #pragma unroll 8
    for (int kk = 0; kk < 32; kk++)
        acc = __builtin_amdgcn_mfma_f32_16x16x32_bf16(Aptr[kk * 4], Bptr[kk * 4], acc, 0, 0, 0);

    int col = n0 + (lane & 15);
    int brb = r0 + (lane >> 4) * 4;
    #pragma unroll
    for (int r = 0; r < 4; r++) {
        int b = brb + r;
        float pre = acc[r] + bf2f(P[((long)t * 64 + b) * N3 + 2048 + col]);
        float hc = tanhf(pre);
        float z  = zbuf[b * 1024 + col];
        float ho = h[b * 1024 + col];
        float hn = (1.f - z) * ho + z * hc;
        h[b * 1024 + col]  = hn;
        hb[b * 1024 + col] = f2bf(hn);
        out[((long)b * T_ + t) * 1024 + col] = hn;
    }
}

extern "C" void kernel_launch(void* const* d_in, const int* in_sizes, int n_in,
                              void* d_out, int out_size, void* d_ws, size_t ws_size,
                              hipStream_t stream)
{
    (void)in_sizes; (void)n_in; (void)out_size; (void)ws_size;
    const float* X   = (const float*)d_in[0];
    const float* h0  = (const float*)d_in[1];
    const float* W_r = (const float*)d_in[2];
    const float* U_r = (const float*)d_in[3];
    const float* C_r = (const float*)d_in[4];
    const float* W_z = (const float*)d_in[5];
    const float* U_z = (const float*)d_in[6];
    const float* C_z = (const float*)d_in[7];
    const float* W   = (const float*)d_in[8];
    const float* U   = (const float*)d_in[9];
    const float* C   = (const float*)d_in[10];

    char* ws = (char*)d_ws;
    size_t off = 0;
    short* WcatT = (short*)(ws + off); off += (size_t)N3 * KIN * 2;
    short* UcatT = (short*)(ws + off); off += (size_t)2048 * 1024 * 2;
    short* UcT   = (short*)(ws + off); off += (size_t)1024 * 1024 * 2;
    short* Xb    = (short*)(ws + off); off += (size_t)M_ * KIN * 2;
    short* P     = (short*)(ws + off); off += (size_t)M_ * N3 * 2;
    float* h     = (float*)(ws + off); off += (size_t)B_ * 1024 * 4;
    short* hb    = (short*)(ws + off); off += (size_t)B_ * 1024 * 2;
    short* rh    = (short*)(ws + off); off += (size_t)B_ * 1024 * 2;
    float* zbuf  = (float*)(ws + off); off += (size_t)B_ * 1024 * 4;
    uint32_t* barcnt = (uint32_t*)(ws + off); off += 128;

    k_prep_w<<<dim3(32, 32, 9), dim3(32, 8), 0, stream>>>(W_r, U_r, C_r, W_z, U_z, C_z, W, U, C,
                                                          WcatT, UcatT, UcT);
    k_prep_x<<<2048, 256, 0, stream>>>(X, Xb, (long)M_ * KIN / 8);
    k_init_h<<<256, 256, 0, stream>>>(h0, h, hb, barcnt);
    k_gemm_x<<<dim3(N3 / 128, M_ / 128), 256, 0, stream>>>(Xb, WcatT, P);

    float* out = (float*)d_out;
    u64* hbU = (u64*)hb;
    u64* rhU = (u64*)rh;
    void* args[] = { (void*)&UcatT, (void*)&UcT, (void*)&P, (void*)&h, (void*)&hbU,
                     (void*)&rhU, (void*)&barcnt, (void*)&out };
    hipError_t e = hipLaunchCooperativeKernel((const void*)k_recur2, dim3(NBLK), dim3(NTHR),
                                              args, 0, stream);
    if (e != hipSuccess) {
        for (int t = 0; t < T_; t++) {
            k_stepA<<<128, 256, 0, stream>>>(hb, UcatT, P, h, rh, zbuf, t);
            k_stepB<<<64, 256, 0, stream>>>(rh, UcT, P, zbuf, h, hb, out, t);
        }
    }
}

// Round 4
// 5338.115 us; speedup vs baseline: 3.3038x; 1.8773x over previous
//
#include <hip/hip_runtime.h>
#include <hip/hip_bf16.h>
#include <stdint.h>

#define B_   64
#define T_   256
#define KIN  2048
#define N3   3072
#define M_   16384
#define NBLK 32
#define NTHR 512

typedef __attribute__((ext_vector_type(8))) short short8;
typedef __attribute__((ext_vector_type(4))) float f32x4;
typedef unsigned long long u64;

static __device__ __forceinline__ float bf2f(short s) {
    union { float f; uint32_t u; } c; c.u = ((uint32_t)(uint16_t)s) << 16; return c.f;
}
static __device__ __forceinline__ short f2bf(float f) {
    union { float f; uint32_t u; } c; c.f = f;
    uint32_t u = c.u;
    uint32_t r = (u + 0x7fffu + ((u >> 16) & 1u)) >> 16;   // round-nearest-even
    return (short)(uint16_t)r;
}

// coherent (bypass L1+L2) 16B load / 8B store — coalesced, batched
#define CLD(dst, ptr) asm volatile("global_load_dwordx4 %0, %1, off sc0 sc1" \
                                   : "=v"(dst) : "v"(ptr))
static __device__ __forceinline__ void cst8(void* p, u64 v) {
    asm volatile("global_store_dwordx2 %0, %1, off sc0 sc1" :: "v"(p), "v"(v) : "memory");
}

// ---------------- prep: weights -> bf16 transposed layouts ----------------
__global__ __launch_bounds__(256)
void k_prep_w(const float* __restrict__ Wr, const float* __restrict__ Ur, const float* __restrict__ Cr,
              const float* __restrict__ Wz, const float* __restrict__ Uz, const float* __restrict__ Cz,
              const float* __restrict__ Wc, const float* __restrict__ Uc, const float* __restrict__ Cc,
              short* __restrict__ WcatT, short* __restrict__ UcatT, short* __restrict__ UcT)
{
    __shared__ float tile[32][33];
    int m = blockIdx.z;
    const float* src; short* dst; int ld, noff, koff;
    switch (m) {
      case 0: src=Cr; dst=WcatT; ld=KIN;  noff=0;    koff=0;    break;
      case 1: src=Wr; dst=WcatT; ld=KIN;  noff=0;    koff=1024; break;
      case 2: src=Cz; dst=WcatT; ld=KIN;  noff=1024; koff=0;    break;
      case 3: src=Wz; dst=WcatT; ld=KIN;  noff=1024; koff=1024; break;
      case 4: src=Cc; dst=WcatT; ld=KIN;  noff=2048; koff=0;    break;
      case 5: src=Wc; dst=WcatT; ld=KIN;  noff=2048; koff=1024; break;
      case 6: src=Ur; dst=UcatT; ld=1024; noff=0;    koff=0;    break;
      case 7: src=Uz; dst=UcatT; ld=1024; noff=1024; koff=0;    break;
      default: src=Uc; dst=UcT;  ld=1024; noff=0;    koff=0;    break;
    }
    int n0 = blockIdx.x * 32, k0 = blockIdx.y * 32;
    int tx = threadIdx.x, ty = threadIdx.y;      // block (32,8)
    #pragma unroll
    for (int i = 0; i < 32; i += 8)
        tile[ty + i][tx] = src[(long)(k0 + ty + i) * 1024 + (n0 + tx)];
    __syncthreads();
    #pragma unroll
    for (int i = 0; i < 32; i += 8)
        dst[(long)(noff + n0 + ty + i) * ld + koff + k0 + tx] = f2bf(tile[tx][ty + i]);
}

// ---------------- prep: X -> bf16 ----------------
__global__ __launch_bounds__(256)
void k_prep_x(const float* __restrict__ X, short* __restrict__ Xb, long n8)
{
    long i = (long)blockIdx.x * blockDim.x + threadIdx.x;
    long stride = (long)gridDim.x * blockDim.x;
    for (; i < n8; i += stride) {
        const float4* p = (const float4*)(X + i * 8);
        float4 a = p[0], b = p[1];
        short8 o;
        o[0]=f2bf(a.x); o[1]=f2bf(a.y); o[2]=f2bf(a.z); o[3]=f2bf(a.w);
        o[4]=f2bf(b.x); o[5]=f2bf(b.y); o[6]=f2bf(b.z); o[7]=f2bf(b.w);
        *(short8*)(Xb + i * 8) = o;
    }
}

__global__ __launch_bounds__(256)
void k_init_h(const float* __restrict__ h0, float* __restrict__ h, short* __restrict__ hb,
              uint32_t* __restrict__ barcnt)
{
    int i = blockIdx.x * 256 + threadIdx.x;   // 256 blocks -> 65536
    float v = h0[i];
    h[i] = v; hb[i] = f2bf(v);
    if (i == 0) *barcnt = 0;
}

// ---------------- phase 1: P = Xb @ Wcat, stored t-major: P[(t*64+b)][n] ----------------
__global__ __launch_bounds__(256)
void k_gemm_x(const short* __restrict__ Xb, const short* __restrict__ WcatT, short* __restrict__ P)
{
    __shared__ short As[128 * 64];
    __shared__ short Bs[128 * 64];
    int tid = threadIdx.x;
    int lane = tid & 63, wave = tid >> 6;
    int i0 = blockIdx.y * 128;    // M block
    int n0 = blockIdx.x * 128;    // N block
    int wrow = (wave >> 1) * 64, wcol = (wave & 1) * 64;
    f32x4 acc[4][4] = {};

    for (int k0 = 0; k0 < KIN; k0 += 64) {
        __syncthreads();
        #pragma unroll
        for (int j = 0; j < 4; j++) {
            int e = (j * 256 + tid) * 8;
            int row = e >> 6, k = e & 63;
            short8 va = *(const short8*)(Xb    + (long)(i0 + row) * KIN + k0 + k);
            short8 vb = *(const short8*)(WcatT + (long)(n0 + row) * KIN + k0 + k);
            int byt = row * 128 + ((k * 2) ^ ((row & 7) << 4));   // XOR swizzle
            *(short8*)((char*)As + byt) = va;
            *(short8*)((char*)Bs + byt) = vb;
        }
        __syncthreads();
        #pragma unroll
        for (int kk = 0; kk < 64; kk += 32) {
            short8 af[4], bfr[4];
            int kel = kk + (lane >> 4) * 8;
            #pragma unroll
            for (int rt = 0; rt < 4; rt++) {
                int row = wrow + rt * 16 + (lane & 15);
                int byt = row * 128 + ((kel * 2) ^ ((row & 7) << 4));
                af[rt] = *(const short8*)((const char*)As + byt);
            }
            #pragma unroll
            for (int ct = 0; ct < 4; ct++) {
                int row = wcol + ct * 16 + (lane & 15);
                int byt = row * 128 + ((kel * 2) ^ ((row & 7) << 4));
                bfr[ct] = *(const short8*)((const char*)Bs + byt);
            }
            #pragma unroll
            for (int rt = 0; rt < 4; rt++)
                #pragma unroll
                for (int ct = 0; ct < 4; ct++)
                    acc[rt][ct] = __builtin_amdgcn_mfma_f32_16x16x32_bf16(af[rt], bfr[ct], acc[rt][ct], 0, 0, 0);
        }
    }
    #pragma unroll
    for (int rt = 0; rt < 4; rt++)
      #pragma unroll
      for (int ct = 0; ct < 4; ct++)
        #pragma unroll
        for (int r = 0; r < 4; r++) {
            int row = i0 + wrow + rt * 16 + (lane >> 4) * 4 + r;   // = b*256 + t
            int prow = ((row & 255) << 6) | (row >> 8);            // t*64 + b
            int col = n0 + wcol + ct * 16 + (lane & 15);
            P[(long)prow * N3 + col] = f2bf(acc[rt][ct][r]);
        }
}

// ---------------- grid barrier (relaxed agent atomics; release via vmcnt drain) ----------------
static __device__ __forceinline__ void gbar(uint32_t* barcnt, uint32_t* bseq)
{
    asm volatile("s_waitcnt vmcnt(0)" ::: "memory");   // publishes at coherence point
    __syncthreads();
    *bseq += 1;
    if (threadIdx.x == 0) {
        __hip_atomic_fetch_add(barcnt, 1u, __ATOMIC_RELAXED, __HIP_MEMORY_SCOPE_AGENT);
        uint32_t tgt = *bseq * (uint32_t)NBLK;
        while (__hip_atomic_load(barcnt, __ATOMIC_RELAXED, __HIP_MEMORY_SCOPE_AGENT) < tgt) { }
    }
    __syncthreads();
}

// stage 32 rows x 1024 bf16 (64KB, contiguous in src) into XOR-swizzled LDS
static __device__ __forceinline__ void stage32(const char* src, char* stg, int tid)
{
    short8 v0,v1,v2,v3,v4,v5,v6,v7;
    CLD(v0, src + (tid +   0) * 16);
    CLD(v1, src + (tid +  512) * 16);
    CLD(v2, src + (tid + 1024) * 16);
    CLD(v3, src + (tid + 1536) * 16);
    CLD(v4, src + (tid + 2048) * 16);
    CLD(v5, src + (tid + 2560) * 16);
    CLD(v6, src + (tid + 3072) * 16);
    CLD(v7, src + (tid + 3584) * 16);
    asm volatile("s_waitcnt vmcnt(0)" ::: "memory");
    #pragma unroll
    for (int i = 0; i < 8; i++) {
        int s = tid + i * 512;
        int row = s >> 7, q = s & 127;
        int off = row * 2048 + ((q * 16) ^ ((row & 7) << 4));
        short8 val = (i==0)?v0:(i==1)?v1:(i==2)?v2:(i==3)?v3:(i==4)?v4:(i==5)?v5:(i==6)?v6:v7;
        *(short8*)(stg + off) = val;
    }
}

// ---------------- persistent recurrence kernel ----------------
// 32 blocks (2 batch-groups x 16 col-groups) x 512 thr (8 waves).
// Block (bg,cg): batch rows [bg*32,+32), hidden cols [cg*64,+64).
// Phase A: waves 0-3 -> r strips, 4-7 -> z strips (each 32x16, K=1024 over staged hb).
// Phase B: wave w -> 16x16 cand tile (rows (w>>2)*16, cols (w&3)*16) over staged rh.
__global__ __launch_bounds__(NTHR)
void k_recur2(const short* __restrict__ UcatT, const short* __restrict__ UcT,
              const short* __restrict__ P, const float* __restrict__ hG,
              u64* __restrict__ hbG, u64* __restrict__ rhG,
              uint32_t* __restrict__ barcnt, float* __restrict__ out)
{
    __shared__ short stage[32 * 1024];    // 64 KB
    __shared__ float h_lds[32 * 65];
    __shared__ float z_lds[32 * 65];
    __shared__ short tscr[8 * 256];

    const int tid  = threadIdx.x;
    const int lane = tid & 63, w = tid >> 6;
    const int col16 = lane & 15, rquad = (lane >> 4) * 4;
    const int lrow = lane & 15, lk = (lane >> 4) * 8;
    const int bg = blockIdx.x >> 4;          // 0..1
    const int Cb = (blockIdx.x & 15) * 64;   // own col base

    for (int i = tid; i < 32 * 64; i += NTHR) {
        int row = i >> 6, cl = i & 63;
        h_lds[row * 65 + cl] = hG[(bg * 32 + row) * 1024 + Cb + cl];
    }

    const int nrowA = (w < 4) ? (Cb + w * 16) : (1024 + Cb + (w - 4) * 16);
    const short* BbaseA = UcatT + (nrowA + lrow) * 1024 + lk;
    const int rowB0 = (w >> 2) * 16, clB0 = (w & 3) * 16;
    const short* BbaseB = UcT + (Cb + clB0 + lrow) * 1024 + lk;

    uint32_t bseq = 0;

    for (int t = 0; t < T_; t++) {
        // ======== phase A: rz = hardsig(P_rz + h @ U_rz) ========
        float pv[2][4];
        {
            const short* Pb = P + ((long)t * 64 + bg * 32) * N3 + nrowA + col16;
            #pragma unroll
            for (int rt = 0; rt < 2; rt++)
                #pragma unroll
                for (int r = 0; r < 4; r++)
                    pv[rt][r] = bf2f(Pb[(rt * 16 + rquad + r) * N3]);
        }
        stage32((const char*)hbG + bg * 65536, (char*)stage, tid);
        __syncthreads();

        f32x4 acc[2] = {};
        #pragma unroll
        for (int kk = 0; kk < 32; kk++) {
            short8 bfv = *(const short8*)(BbaseA + kk * 32);
            int kb = (kk * 64 + (lane >> 4) * 16);
            #pragma unroll
            for (int rt = 0; rt < 2; rt++) {
                int row = rt * 16 + lrow;
                short8 af = *(const short8*)((const char*)stage + row * 2048 + (kb ^ ((row & 7) << 4)));
                acc[rt] = __builtin_amdgcn_mfma_f32_16x16x32_bf16(af, bfv, acc[rt], 0, 0, 0);
            }
        }

        if (w < 4) {                       // r-waves: rh = r*h, publish k-contiguous
            int cl0 = w * 16;
            #pragma unroll
            for (int rt = 0; rt < 2; rt++) {
                #pragma unroll
                for (int r = 0; r < 4; r++) {
                    int lr = rt * 16 + rquad + r;
                    float pre = acc[rt][r] + pv[rt][r];
                    float v = fminf(fmaxf(0.2f * pre + 0.5f, 0.f), 1.f);
                    tscr[w * 256 + (rquad + r) * 16 + col16] = f2bf(v * h_lds[lr * 65 + cl0 + col16]);
                }
                asm volatile("s_waitcnt lgkmcnt(0)" ::: "memory");
                u64 vv = *(const u64*)((const char*)tscr + w * 512 + (lane & 15) * 32 + (lane >> 4) * 8);
                asm volatile("s_waitcnt lgkmcnt(0)" ::: "memory");
                int rowl = rt * 16 + (lane & 15);
                cst8(rhG + (bg * 32 + rowl) * 256 + (Cb >> 2) + w * 4 + (lane >> 4), vv);
            }
        } else {                           // z-waves: z block-local
            int cl0 = (w - 4) * 16;
            #pragma unroll
            for (int rt = 0; rt < 2; rt++)
                #pragma unroll
                for (int r = 0; r < 4; r++) {
                    int lr = rt * 16 + rquad + r;
                    float pre = acc[rt][r] + pv[rt][r];
                    z_lds[lr * 65 + cl0 + col16] = fminf(fmaxf(0.2f * pre + 0.5f, 0.f), 1.f);
                }
        }
        gbar(barcnt, &bseq);

        // ======== phase B: hc = tanh(P_c + rh @ U); h update ========
        float pv2[4];
        {
            const short* Pb = P + ((long)t * 64 + bg * 32 + rowB0) * N3 + 2048 + Cb + clB0 + col16;
            #pragma unroll
            for (int r = 0; r < 4; r++)
                pv2[r] = bf2f(Pb[(rquad + r) * N3]);
        }
        stage32((const char*)rhG + bg * 65536, (char*)stage, tid);
        __syncthreads();

        f32x4 acc2 = {};
        #pragma unroll
        for (int kk = 0; kk < 32; kk++) {
            short8 bfv = *(const short8*)(BbaseB + kk * 32);
            int kb = (kk * 64 + (lane >> 4) * 16);
            int row = rowB0 + lrow;
            short8 af = *(const short8*)((const char*)stage + row * 2048 + (kb ^ ((row & 7) << 4)));
            acc2 = __builtin_amdgcn_mfma_f32_16x16x32_bf16(af, bfv, acc2, 0, 0, 0);
        }

        #pragma unroll
        for (int r = 0; r < 4; r++) {
            int lr = rowB0 + rquad + r;
            float pre = acc2[r] + pv2[r];
            float hc = tanhf(pre);
            float z  = z_lds[lr * 65 + clB0 + col16];
            float ho = h_lds[lr * 65 + clB0 + col16];
            float hn = (1.f - z) * ho + z * hc;
            h_lds[lr * 65 + clB0 + col16] = hn;
            out[((long)(bg * 32 + lr) * T_ + t) * 1024 + Cb + clB0 + col16] = hn;
            tscr[w * 256 + (rquad + r) * 16 + col16] = f2bf(hn);
        }
        asm volatile("s_waitcnt lgkmcnt(0)" ::: "memory");
        u64 vv = *(const u64*)((const char*)tscr + w * 512 + (lane & 15) * 32 + (lane >> 4) * 8);
        asm volatile("s_waitcnt lgkmcnt(0)" ::: "memory");
        int rowl = rowB0 + (lane & 15);
        cst8(hbG + (bg * 32 + rowl) * 256 + (Cb >> 2) + (w & 3) * 4 + (lane >> 4), vv);

        gbar(barcnt, &bseq);
    }
}

// ---------------- fallback per-step kernels (t-major P) ----------------
__global__ __launch_bounds__(256)
void k_stepA(const short* __restrict__ hb, const short* __restrict__ UcatT,
             const short* __restrict__ P, const float* __restrict__ h,
             short* __restrict__ rh, float* __restrict__ zbuf, int t)
{
    int lane = threadIdx.x & 63, wave = threadIdx.x >> 6;
    int wid = blockIdx.x * 4 + wave;
    int ct = wid & 127, rt = wid >> 7;
    int r0 = rt * 16, n0 = ct * 16;
    int lrow = lane & 15, lk = (lane >> 4) * 8;
    f32x4 acc = {0.f, 0.f, 0.f, 0.f};
    const short8* Aptr = (const short8*)(hb    + (r0 + lrow) * 1024 + lk);
    const short8* Bptr = (const short8*)(UcatT + (n0 + lrow) * 1024 + lk);
    #pragma unroll 8
    for (int kk = 0; kk < 32; kk++)
        acc = __builtin_amdgcn_mfma_f32_16x16x32_bf16(Aptr[kk * 4], Bptr[kk * 4], acc, 0, 0, 0);

    int col = n0 + (lane & 15);
    int brb = r0 + (lane >> 4) * 4;
    #pragma unroll
    for (int r = 0; r < 4; r++) {
        int b = brb + r;
        float pre = acc[r] + bf2f(P[((long)t * 64 + b) * N3 + col]);
        float v = fminf(fmaxf(0.2f * pre + 0.5f, 0.f), 1.f);
        if (col < 1024)
            rh[b * 1024 + col] = f2bf(v * h[b * 1024 + col]);
        else
            zbuf[b * 1024 + (col - 1024)] = v;
    }
}

__global__ __launch_bounds__(256)
void k_stepB(const short* __restrict__ rh, const short* __restrict__ UcT,
             const short* __restrict__ P, const float* __restrict__ zbuf,
             float* __restrict__ h, short* __restrict__ hb,
             float* __restrict__ out, int t)
{
    int lane = threadIdx.x & 63, wave = threadIdx.x >> 6;
    int wid = blockIdx.x * 4 + wave;
    int ct = wid & 63, rt = wid >> 6;
    int r0 = rt * 16, n0 = ct * 16;
    int lrow = lane & 15, lk = (lane >> 4) * 8;
    f32x4 acc = {0.f, 0.f, 0.f, 0.f};
    const short8* Aptr = (const short8*)(rh  + (r0 + lrow) * 1024 + lk);
    const short8* Bptr = (const short8*)(UcT + (n0 + lrow) * 1024 + lk);
    #pragma unroll 8
    for (int kk = 0; kk < 32; kk++)
        acc = __builtin_amdgcn_mfma_f32_16x16x32_bf16(Aptr[kk * 4], Bptr[kk * 4], acc, 0, 0, 0);

    int col = n0 + (lane & 15);
    int brb = r0 + (lane >> 4) * 4;
    #pragma unroll
    for (int r = 0; r < 4; r++) {
        int b = brb + r;
        float pre = acc[r] + bf2f(P[((long)t * 64 + b) * N3 + 2048 + col]);
        float hc = tanhf(pre);
        float z  = zbuf[b * 1024 + col];
        float ho = h[b * 1024 + col];
        float hn = (1.f - z) * ho + z * hc;
        h[b * 1024 + col]  = hn;
        hb[b * 1024 + col] = f2bf(hn);
        out[((long)b * T_ + t) * 1024 + col] = hn;
    }
}

extern "C" void kernel_launch(void* const* d_in, const int* in_sizes, int n_in,
                              void* d_out, int out_size, void* d_ws, size_t ws_size,
                              hipStream_t stream)
{
    (void)in_sizes; (void)n_in; (void)out_size; (void)ws_size;
    const float* X   = (const float*)d_in[0];
    const float* h0  = (const float*)d_in[1];
    const float* W_r = (const float*)d_in[2];
    const float* U_r = (const float*)d_in[3];
    const float* C_r = (const float*)d_in[4];
    const float* W_z = (const float*)d_in[5];
    const float* U_z = (const float*)d_in[6];
    const float* C_z = (const float*)d_in[7];
    const float* W   = (const float*)d_in[8];
    const float* U   = (const float*)d_in[9];
    const float* C   = (const float*)d_in[10];

    char* ws = (char*)d_ws;
    size_t off = 0;
    short* WcatT = (short*)(ws + off); off += (size_t)N3 * KIN * 2;
    short* UcatT = (short*)(ws + off); off += (size_t)2048 * 1024 * 2;
    short* UcT   = (short*)(ws + off); off += (size_t)1024 * 1024 * 2;
    short* Xb    = (short*)(ws + off); off += (size_t)M_ * KIN * 2;
    short* P     = (short*)(ws + off); off += (size_t)M_ * N3 * 2;
    float* h     = (float*)(ws + off); off += (size_t)B_ * 1024 * 4;
    short* hb    = (short*)(ws + off); off += (size_t)B_ * 1024 * 2;
    short* rh    = (short*)(ws + off); off += (size_t)B_ * 1024 * 2;
    float* zbuf  = (float*)(ws + off); off += (size_t)B_ * 1024 * 4;
    uint32_t* barcnt = (uint32_t*)(ws + off); off += 128;

    k_prep_w<<<dim3(32, 32, 9), dim3(32, 8), 0, stream>>>(W_r, U_r, C_r, W_z, U_z, C_z, W, U, C,
                                                          WcatT, UcatT, UcT);
    k_prep_x<<<2048, 256, 0, stream>>>(X, Xb, (long)M_ * KIN / 8);
    k_init_h<<<256, 256, 0, stream>>>(h0, h, hb, barcnt);
    k_gemm_x<<<dim3(N3 / 128, M_ / 128), 256, 0, stream>>>(Xb, WcatT, P);

    float* out = (float*)d_out;
    u64* hbU = (u64*)hb;
    u64* rhU = (u64*)rh;
    void* args[] = { (void*)&UcatT, (void*)&UcT, (void*)&P, (void*)&h, (void*)&hbU,
                     (void*)&rhU, (void*)&barcnt, (void*)&out };
    hipError_t e = hipLaunchCooperativeKernel((const void*)k_recur2, dim3(NBLK), dim3(NTHR),
                                              args, 0, stream);
    if (e != hipSuccess) {
        for (int t = 0; t < T_; t++) {
            k_stepA<<<128, 256, 0, stream>>>(hb, UcatT, P, h, rh, zbuf, t);
            k_stepB<<<64, 256, 0, stream>>>(rh, UcT, P, zbuf, h, hb, out, t);
        }
    }
}

// Round 5
// 5277.018 us; speedup vs baseline: 3.3421x; 1.0116x over previous
//
#include <hip/hip_runtime.h>
#include <hip/hip_bf16.h>
#include <stdint.h>

#define B_   64
#define T_   256
#define KIN  2048
#define N3   3072
#define M_   16384
#define NBLK 32
#define NTHR 512

typedef __attribute__((ext_vector_type(8))) short short8;
typedef __attribute__((ext_vector_type(4))) float f32x4;
typedef unsigned long long u64;

static __device__ __forceinline__ float bf2f(short s) {
    union { float f; uint32_t u; } c; c.u = ((uint32_t)(uint16_t)s) << 16; return c.f;
}
static __device__ __forceinline__ short f2bf(float f) {
    union { float f; uint32_t u; } c; c.f = f;
    uint32_t u = c.u;
    uint32_t r = (u + 0x7fffu + ((u >> 16) & 1u)) >> 16;   // round-nearest-even
    return (short)(uint16_t)r;
}

// coherent (bypass L1+L2) 16B load / 8B store — coalesced, batched
#define CLD(dst, ptr) asm volatile("global_load_dwordx4 %0, %1, off sc0 sc1" \
                                   : "=v"(dst) : "v"(ptr))
static __device__ __forceinline__ void cst8(void* p, u64 v) {
    asm volatile("global_store_dwordx2 %0, %1, off sc0 sc1" :: "v"(p), "v"(v) : "memory");
}

// ---------------- prep: weights -> bf16 transposed layouts ----------------
__global__ __launch_bounds__(256)
void k_prep_w(const float* __restrict__ Wr, const float* __restrict__ Ur, const float* __restrict__ Cr,
              const float* __restrict__ Wz, const float* __restrict__ Uz, const float* __restrict__ Cz,
              const float* __restrict__ Wc, const float* __restrict__ Uc, const float* __restrict__ Cc,
              short* __restrict__ WcatT, short* __restrict__ UcatT, short* __restrict__ UcT)
{
    __shared__ float tile[32][33];
    int m = blockIdx.z;
    const float* src; short* dst; int ld, noff, koff;
    switch (m) {
      case 0: src=Cr; dst=WcatT; ld=KIN;  noff=0;    koff=0;    break;
      case 1: src=Wr; dst=WcatT; ld=KIN;  noff=0;    koff=1024; break;
      case 2: src=Cz; dst=WcatT; ld=KIN;  noff=1024; koff=0;    break;
      case 3: src=Wz; dst=WcatT; ld=KIN;  noff=1024; koff=1024; break;
      case 4: src=Cc; dst=WcatT; ld=KIN;  noff=2048; koff=0;    break;
      case 5: src=Wc; dst=WcatT; ld=KIN;  noff=2048; koff=1024; break;
      case 6: src=Ur; dst=UcatT; ld=1024; noff=0;    koff=0;    break;
      case 7: src=Uz; dst=UcatT; ld=1024; noff=1024; koff=0;    break;
      default: src=Uc; dst=UcT;  ld=1024; noff=0;    koff=0;    break;
    }
    int n0 = blockIdx.x * 32, k0 = blockIdx.y * 32;
    int tx = threadIdx.x, ty = threadIdx.y;      // block (32,8)
    #pragma unroll
    for (int i = 0; i < 32; i += 8)
        tile[ty + i][tx] = src[(long)(k0 + ty + i) * 1024 + (n0 + tx)];
    __syncthreads();
    #pragma unroll
    for (int i = 0; i < 32; i += 8)
        dst[(long)(noff + n0 + ty + i) * ld + koff + k0 + tx] = f2bf(tile[tx][ty + i]);
}

// ---------------- prep: X -> bf16 ----------------
__global__ __launch_bounds__(256)
void k_prep_x(const float* __restrict__ X, short* __restrict__ Xb, long n8)
{
    long i = (long)blockIdx.x * blockDim.x + threadIdx.x;
    long stride = (long)gridDim.x * blockDim.x;
    for (; i < n8; i += stride) {
        const float4* p = (const float4*)(X + i * 8);
        float4 a = p[0], b = p[1];
        short8 o;
        o[0]=f2bf(a.x); o[1]=f2bf(a.y); o[2]=f2bf(a.z); o[3]=f2bf(a.w);
        o[4]=f2bf(b.x); o[5]=f2bf(b.y); o[6]=f2bf(b.z); o[7]=f2bf(b.w);
        *(short8*)(Xb + i * 8) = o;
    }
}

__global__ __launch_bounds__(256)
void k_init_h(const float* __restrict__ h0, float* __restrict__ h, short* __restrict__ hb,
              uint32_t* __restrict__ flags)
{
    int i = blockIdx.x * 256 + threadIdx.x;   // 256 blocks -> 65536
    float v = h0[i];
    h[i] = v; hb[i] = f2bf(v);
    if (i < 1024) flags[i] = 0;
}

// ---------------- phase 1: P = Xb @ Wcat, stored t-major: P[(t*64+b)][n] ----------------
__global__ __launch_bounds__(256)
void k_gemm_x(const short* __restrict__ Xb, const short* __restrict__ WcatT, short* __restrict__ P)
{
    __shared__ short As[128 * 64];
    __shared__ short Bs[128 * 64];
    int tid = threadIdx.x;
    int lane = tid & 63, wave = tid >> 6;
    int i0 = blockIdx.y * 128;    // M block
    int n0 = blockIdx.x * 128;    // N block
    int wrow = (wave >> 1) * 64, wcol = (wave & 1) * 64;
    f32x4 acc[4][4] = {};

    for (int k0 = 0; k0 < KIN; k0 += 64) {
        __syncthreads();
        #pragma unroll
        for (int j = 0; j < 4; j++) {
            int e = (j * 256 + tid) * 8;
            int row = e >> 6, k = e & 63;
            short8 va = *(const short8*)(Xb    + (long)(i0 + row) * KIN + k0 + k);
            short8 vb = *(const short8*)(WcatT + (long)(n0 + row) * KIN + k0 + k);
            int byt = row * 128 + ((k * 2) ^ ((row & 7) << 4));   // XOR swizzle
            *(short8*)((char*)As + byt) = va;
            *(short8*)((char*)Bs + byt) = vb;
        }
        __syncthreads();
        #pragma unroll
        for (int kk = 0; kk < 64; kk += 32) {
            short8 af[4], bfr[4];
            int kel = kk + (lane >> 4) * 8;
            #pragma unroll
            for (int rt = 0; rt < 4; rt++) {
                int row = wrow + rt * 16 + (lane & 15);
                int byt = row * 128 + ((kel * 2) ^ ((row & 7) << 4));
                af[rt] = *(const short8*)((const char*)As + byt);
            }
            #pragma unroll
            for (int ct = 0; ct < 4; ct++) {
                int row = wcol + ct * 16 + (lane & 15);
                int byt = row * 128 + ((kel * 2) ^ ((row & 7) << 4));
                bfr[ct] = *(const short8*)((const char*)Bs + byt);
            }
            #pragma unroll
            for (int rt = 0; rt < 4; rt++)
                #pragma unroll
                for (int ct = 0; ct < 4; ct++)
                    acc[rt][ct] = __builtin_amdgcn_mfma_f32_16x16x32_bf16(af[rt], bfr[ct], acc[rt][ct], 0, 0, 0);
        }
    }
    #pragma unroll
    for (int rt = 0; rt < 4; rt++)
      #pragma unroll
      for (int ct = 0; ct < 4; ct++)
        #pragma unroll
        for (int r = 0; r < 4; r++) {
            int row = i0 + wrow + rt * 16 + (lane >> 4) * 4 + r;   // = b*256 + t
            int prow = ((row & 255) << 6) | (row >> 8);            // t*64 + b
            int col = n0 + wcol + ct * 16 + (lane & 15);
            P[(long)prow * N3 + col] = f2bf(acc[rt][ct][r]);
        }
}

// ---------------- distributed-flag grid barrier (no RMW, padded lines) ----------------
// flags[blk*32] holds that block's sequence number (128B apart -> no line sharing).
static __device__ __forceinline__ void gbar2(uint32_t* flags, uint32_t seq)
{
    asm volatile("s_waitcnt vmcnt(0)" ::: "memory");   // this wave's stores at coherence point
    __syncthreads();                                    // => all waves' stores done
    if (threadIdx.x == 0)
        __hip_atomic_store(flags + blockIdx.x * 32, seq, __ATOMIC_RELAXED, __HIP_MEMORY_SCOPE_AGENT);
    if (threadIdx.x < 64) {
        int l = threadIdx.x;
        for (;;) {
            uint32_t v = (l < NBLK)
                ? __hip_atomic_load(flags + l * 32, __ATOMIC_RELAXED, __HIP_MEMORY_SCOPE_AGENT)
                : seq;
            if (__all((int)(v >= seq))) break;
        }
    }
    __syncthreads();
}

// stage 32 rows x 1024 bf16 (64KB, contiguous in src) into XOR-swizzled LDS
static __device__ __forceinline__ void stage32(const char* src, char* stg, int tid)
{
    short8 v0,v1,v2,v3,v4,v5,v6,v7;
    CLD(v0, src + (tid +   0) * 16);
    CLD(v1, src + (tid +  512) * 16);
    CLD(v2, src + (tid + 1024) * 16);
    CLD(v3, src + (tid + 1536) * 16);
    CLD(v4, src + (tid + 2048) * 16);
    CLD(v5, src + (tid + 2560) * 16);
    CLD(v6, src + (tid + 3072) * 16);
    CLD(v7, src + (tid + 3584) * 16);
    asm volatile("s_waitcnt vmcnt(0)" ::: "memory");
    #pragma unroll
    for (int i = 0; i < 8; i++) {
        int s = tid + i * 512;
        int row = s >> 7, q = s & 127;
        int off = row * 2048 + ((q * 16) ^ ((row & 7) << 4));
        short8 val = (i==0)?v0:(i==1)?v1:(i==2)?v2:(i==3)?v3:(i==4)?v4:(i==5)?v5:(i==6)?v6:v7;
        *(short8*)(stg + off) = val;
    }
}

// ---------------- persistent recurrence kernel ----------------
// 32 blocks (2 batch-groups x 16 col-groups) x 512 thr (8 waves).
__global__ __launch_bounds__(NTHR)
void k_recur2(const short* __restrict__ UcatT, const short* __restrict__ UcT,
              const short* __restrict__ P, const float* __restrict__ hG,
              u64* __restrict__ hbG, u64* __restrict__ rhG,
              uint32_t* __restrict__ flags, float* __restrict__ out)
{
    __shared__ short stage[32 * 1024];    // 64 KB
    __shared__ float h_lds[32 * 65];
    __shared__ float z_lds[32 * 65];
    __shared__ short tscr[8 * 320];       // padded: 16 rows x 20 shorts per wave

    const int tid  = threadIdx.x;
    const int lane = tid & 63, w = tid >> 6;
    const int col16 = lane & 15, rquad = (lane >> 4) * 4;
    const int lrow = lane & 15, lk = (lane >> 4) * 8;
    const int bg = blockIdx.x >> 4;          // 0..1
    const int Cb = (blockIdx.x & 15) * 64;   // own col base

    for (int i = tid; i < 32 * 64; i += NTHR) {
        int row = i >> 6, cl = i & 63;
        h_lds[row * 65 + cl] = hG[(bg * 32 + row) * 1024 + Cb + cl];
    }

    const int nrowA = (w < 4) ? (Cb + w * 16) : (1024 + Cb + (w - 4) * 16);
    const short* BbaseA = UcatT + (nrowA + lrow) * 1024 + lk;
    const int rowB0 = (w >> 2) * 16, clB0 = (w & 3) * 16;
    const short* BbaseB = UcT + (Cb + clB0 + lrow) * 1024 + lk;

    uint32_t bseq = 0;

    // prefetch pvA for t=0
    float pvA[2][4];
    {
        const short* Pb = P + (long)(bg * 32) * N3 + nrowA + col16;
        #pragma unroll
        for (int rt = 0; rt < 2; rt++)
            #pragma unroll
            for (int r = 0; r < 4; r++)
                pvA[rt][r] = bf2f(Pb[(rt * 16 + rquad + r) * N3]);
    }

    for (int t = 0; t < T_; t++) {
        // ======== phase A: rz = hardsig(P_rz + h @ U_rz) ========
        stage32((const char*)hbG + bg * 65536, (char*)stage, tid);
        __syncthreads();

        // prefetch pvB(t) — plain loads, retire inside this phase's gbar
        float pvB[4];
        {
            const short* Pb = P + ((long)t * 64 + bg * 32 + rowB0) * N3 + 2048 + Cb + clB0 + col16;
            #pragma unroll
            for (int r = 0; r < 4; r++)
                pvB[r] = bf2f(Pb[(rquad + r) * N3]);
        }

        f32x4 acc[2] = {};
        #pragma unroll
        for (int kk = 0; kk < 32; kk++) {
            short8 bfv = *(const short8*)(BbaseA + kk * 32);
            int kb = (kk * 64 + (lane >> 4) * 16);
            #pragma unroll
            for (int rt = 0; rt < 2; rt++) {
                int row = rt * 16 + lrow;
                short8 af = *(const short8*)((const char*)stage + row * 2048 + (kb ^ ((row & 7) << 4)));
                acc[rt] = __builtin_amdgcn_mfma_f32_16x16x32_bf16(af, bfv, acc[rt], 0, 0, 0);
            }
        }

        if (w < 4) {                       // r-waves: rh = r*h, publish k-contiguous
            int cl0 = w * 16;
            #pragma unroll
            for (int rt = 0; rt < 2; rt++) {
                #pragma unroll
                for (int r = 0; r < 4; r++) {
                    int lr = rt * 16 + rquad + r;
                    float pre = acc[rt][r] + pvA[rt][r];
                    float v = fminf(fmaxf(0.2f * pre + 0.5f, 0.f), 1.f);
                    tscr[w * 320 + (rquad + r) * 20 + col16] = f2bf(v * h_lds[lr * 65 + cl0 + col16]);
                }
                asm volatile("s_waitcnt lgkmcnt(0)" ::: "memory");
                u64 vv = *(const u64*)((const char*)tscr + w * 640 + (lane & 15) * 40 + (lane >> 4) * 8);
                asm volatile("s_waitcnt lgkmcnt(0)" ::: "memory");
                int rowl = rt * 16 + (lane & 15);
                cst8(rhG + (bg * 32 + rowl) * 256 + (Cb >> 2) + w * 4 + (lane >> 4), vv);
            }
        } else {                           // z-waves: z block-local
            int cl0 = (w - 4) * 16;
            #pragma unroll
            for (int rt = 0; rt < 2; rt++)
                #pragma unroll
                for (int r = 0; r < 4; r++) {
                    int lr = rt * 16 + rquad + r;
                    float pre = acc[rt][r] + pvA[rt][r];
                    z_lds[lr * 65 + cl0 + col16] = fminf(fmaxf(0.2f * pre + 0.5f, 0.f), 1.f);
                }
        }
        gbar2(flags, ++bseq);

        // ======== phase B: hc = tanh(P_c + rh @ U); h update ========
        stage32((const char*)rhG + bg * 65536, (char*)stage, tid);
        __syncthreads();

        // prefetch pvA(t+1) — clamped address, unused at t=255
        {
            int tn = (t + 1) & 255;
            const short* Pb = P + ((long)tn * 64 + bg * 32) * N3 + nrowA + col16;
            #pragma unroll
            for (int rt = 0; rt < 2; rt++)
                #pragma unroll
                for (int r = 0; r < 4; r++)
                    pvA[rt][r] = bf2f(Pb[(rt * 16 + rquad + r) * N3]);
        }

        f32x4 acc2 = {};
        #pragma unroll
        for (int kk = 0; kk < 32; kk++) {
            short8 bfv = *(const short8*)(BbaseB + kk * 32);
            int kb = (kk * 64 + (lane >> 4) * 16);
            int row = rowB0 + lrow;
            short8 af = *(const short8*)((const char*)stage + row * 2048 + (kb ^ ((row & 7) << 4)));
            acc2 = __builtin_amdgcn_mfma_f32_16x16x32_bf16(af, bfv, acc2, 0, 0, 0);
        }

        #pragma unroll
        for (int r = 0; r < 4; r++) {
            int lr = rowB0 + rquad + r;
            float pre = acc2[r] + pvB[r];
            float hc = tanhf(pre);
            float z  = z_lds[lr * 65 + clB0 + col16];
            float ho = h_lds[lr * 65 + clB0 + col16];
            float hn = (1.f - z) * ho + z * hc;
            h_lds[lr * 65 + clB0 + col16] = hn;
            out[((long)(bg * 32 + lr) * T_ + t) * 1024 + Cb + clB0 + col16] = hn;
            tscr[w * 320 + (rquad + r) * 20 + col16] = f2bf(hn);
        }
        asm volatile("s_waitcnt lgkmcnt(0)" ::: "memory");
        u64 vv = *(const u64*)((const char*)tscr + w * 640 + (lane & 15) * 40 + (lane >> 4) * 8);
        asm volatile("s_waitcnt lgkmcnt(0)" ::: "memory");
        int rowl = rowB0 + (lane & 15);
        cst8(hbG + (bg * 32 + rowl) * 256 + (Cb >> 2) + (w & 3) * 4 + (lane >> 4), vv);

        gbar2(flags, ++bseq);
    }
}

// ---------------- fallback per-step kernels (t-major P) ----------------
__global__ __launch_bounds__(256)
void k_stepA(const short* __restrict__ hb, const short* __restrict__ UcatT,
             const short* __restrict__ P, const float* __restrict__ h,
             short* __restrict__ rh, float* __restrict__ zbuf, int t)
{
    int lane = threadIdx.x & 63, wave = threadIdx.x >> 6;
    int wid = blockIdx.x * 4 + wave;
    int ct = wid & 127, rt = wid >> 7;
    int r0 = rt * 16, n0 = ct * 16;
    int lrow = lane & 15, lk = (lane >> 4) * 8;
    f32x4 acc = {0.f, 0.f, 0.f, 0.f};
    const short8* Aptr = (const short8*)(hb    + (r0 + lrow) * 1024 + lk);
    const short8* Bptr = (const short8*)(UcatT + (n0 + lrow) * 1024 + lk);
    #pragma unroll 8
    for (int kk = 0; kk < 32; kk++)
        acc = __builtin_amdgcn_mfma_f32_16x16x32_bf16(Aptr[kk * 4], Bptr[kk * 4], acc, 0, 0, 0);

    int col = n0 + (lane & 15);
    int brb = r0 + (lane >> 4) * 4;
    #pragma unroll
    for (int r = 0; r < 4; r++) {
        int b = brb + r;
        float pre = acc[r] + bf2f(P[((long)t * 64 + b) * N3 + col]);
        float v = fminf(fmaxf(0.2f * pre + 0.5f, 0.f), 1.f);
        if (col < 1024)
            rh[b * 1024 + col] = f2bf(v * h[b * 1024 + col]);
        else
            zbuf[b * 1024 + (col - 1024)] = v;
    }
}

__global__ __launch_bounds__(256)
void k_stepB(const short* __restrict__ rh, const short* __restrict__ UcT,
             const short* __restrict__ P, const float* __restrict__ zbuf,
             float* __restrict__ h, short* __restrict__ hb,
             float* __restrict__ out, int t)
{
    int lane = threadIdx.x & 63, wave = threadIdx.x >> 6;
    int wid = blockIdx.x * 4 + wave;
    int ct = wid & 63, rt = wid >> 6;
    int r0 = rt * 16, n0 = ct * 16;
    int lrow = lane & 15, lk = (lane >> 4) * 8;
    f32x4 acc = {0.f, 0.f, 0.f, 0.f};
    const short8* Aptr = (const short8*)(rh  + (r0 + lrow) * 1024 + lk);
    const short8* Bptr = (const short8*)(UcT + (n0 + lrow) * 1024 + lk);
    #pragma unroll 8
    for (int kk = 0; kk < 32; kk++)
        acc = __builtin_amdgcn_mfma_f32_16x16x32_bf16(Aptr[kk * 4], Bptr[kk * 4], acc, 0, 0, 0);

    int col = n0 + (lane & 15);
    int brb = r0 + (lane >> 4) * 4;
    #pragma unroll
    for (int r = 0; r < 4; r++) {
        int b = brb + r;
        float pre = acc[r] + bf2f(P[((long)t * 64 + b) * N3 + 2048 + col]);
        float hc = tanhf(pre);
        float z  = zbuf[b * 1024 + col];
        float ho = h[b * 1024 + col];
        float hn = (1.f - z) * ho + z * hc;
        h[b * 1024 + col]  = hn;
        hb[b * 1024 + col] = f2bf(hn);
        out[((long)b * T_ + t) * 1024 + col] = hn;
    }
}

extern "C" void kernel_launch(void* const* d_in, const int* in_sizes, int n_in,
                              void* d_out, int out_size, void* d_ws, size_t ws_size,
                              hipStream_t stream)
{
    (void)in_sizes; (void)n_in; (void)out_size; (void)ws_size;
    const float* X   = (const float*)d_in[0];
    const float* h0  = (const float*)d_in[1];
    const float* W_r = (const float*)d_in[2];
    const float* U_r = (const float*)d_in[3];
    const float* C_r = (const float*)d_in[4];
    const float* W_z = (const float*)d_in[5];
    const float* U_z = (const float*)d_in[6];
    const float* C_z = (const float*)d_in[7];
    const float* W   = (const float*)d_in[8];
    const float* U   = (const float*)d_in[9];
    const float* C   = (const float*)d_in[10];

    char* ws = (char*)d_ws;
    size_t off = 0;
    short* WcatT = (short*)(ws + off); off += (size_t)N3 * KIN * 2;
    short* UcatT = (short*)(ws + off); off += (size_t)2048 * 1024 * 2;
    short* UcT   = (short*)(ws + off); off += (size_t)1024 * 1024 * 2;
    short* Xb    = (short*)(ws + off); off += (size_t)M_ * KIN * 2;
    short* P     = (short*)(ws + off); off += (size_t)M_ * N3 * 2;
    float* h     = (float*)(ws + off); off += (size_t)B_ * 1024 * 4;
    short* hb    = (short*)(ws + off); off += (size_t)B_ * 1024 * 2;
    short* rh    = (short*)(ws + off); off += (size_t)B_ * 1024 * 2;
    float* zbuf  = (float*)(ws + off); off += (size_t)B_ * 1024 * 4;
    uint32_t* flags = (uint32_t*)(ws + off); off += 4096;

    k_prep_w<<<dim3(32, 32, 9), dim3(32, 8), 0, stream>>>(W_r, U_r, C_r, W_z, U_z, C_z, W, U, C,
                                                          WcatT, UcatT, UcT);
    k_prep_x<<<2048, 256, 0, stream>>>(X, Xb, (long)M_ * KIN / 8);
    k_init_h<<<256, 256, 0, stream>>>(h0, h, hb, flags);
    k_gemm_x<<<dim3(N3 / 128, M_ / 128), 256, 0, stream>>>(Xb, WcatT, P);

    float* out = (float*)d_out;
    u64* hbU = (u64*)hb;
    u64* rhU = (u64*)rh;
    void* args[] = { (void*)&UcatT, (void*)&UcT, (void*)&P, (void*)&h, (void*)&hbU,
                     (void*)&rhU, (void*)&flags, (void*)&out };
    hipError_t e = hipLaunchCooperativeKernel((const void*)k_recur2, dim3(NBLK), dim3(NTHR),
                                              args, 0, stream);
    if (e != hipSuccess) {
        for (int t = 0; t < T_; t++) {
            k_stepA<<<128, 256, 0, stream>>>(hb, UcatT, P, h, rh, zbuf, t);
            k_stepB<<<64, 256, 0, stream>>>(rh, UcT, P, zbuf, h, hb, out, t);
        }
    }
}